// Round 6
// baseline (142.421 us; speedup 1.0000x reference)
//
#include <hip/hip_runtime.h>
#include <hip/hip_bf16.h>
#include <math.h>

// Problem constants (from reference)
constexpr int B = 8;
constexpr int S = 2048;
constexpr int D = 512;
constexpr int P = 64;
constexpr float SCALE = 0.125f;  // 1/sqrt(P)

typedef short bf16x8 __attribute__((ext_vector_type(8)));
typedef float f32x4 __attribute__((ext_vector_type(4)));
typedef unsigned int u32;

__device__ __forceinline__ unsigned short f2bf(float x) {
  __hip_bfloat16 h = __float2bfloat16(x);
  return __builtin_bit_cast(unsigned short, h);
}
__device__ __forceinline__ float bf2f(unsigned short u) {
  unsigned int v = (unsigned int)u << 16;
  return __builtin_bit_cast(float, v);
}

// ===========================================================================
// Fragment-packed layouts (the core of this round):
// Every MFMA B/A fragment a wave consumes is stored as a contiguous
// 64-lane x 16 B = 1 KB chunk, in lane order (lane = l4*16 + l15 holds
// element [k=l4*8+j][n=l15] for B, [m=l15][k=l4*8+j] for A).  So every
// fragment load is ONE coalesced global_load_dwordx4 from L2 - no LDS
// staging, no barriers, no multi-line gathers.
//
//  Bfrag  [12 ntile][16 k16][64 lane][8]   : WqWkWv cat (192 cols, K=512)
//  Wofrag [32 ct][2 h][64 lane][8]         : Wo (512 cols, K=64)
//  qfrag/kfrag [b][128 tile][2 h][64][8]   : per batch, tile=16 rows, h=K-half
//  vfrag  [b][64 tb][4 pc][64][8]          : tb=32 t's, pc=16 p's (t is K-dim)
// ===========================================================================

// ---------------------------------------------------------------------------
// Kernel 0: weight prep -> fragment-packed bf16.
// ---------------------------------------------------------------------------
__global__ __launch_bounds__(256) void prep_w(
    const float* __restrict__ Wq, const float* __restrict__ Wk,
    const float* __restrict__ Wv, const float* __restrict__ Wo,
    unsigned short* __restrict__ Bfrag, unsigned short* __restrict__ Wofrag) {
  const int i = blockIdx.x * 256 + threadIdx.x;
  if (i < 192 * 512) {
    const int d = i / 192;        // K index 0..511 (coalesced-ish reads)
    const int n = i - d * 192;    // output col 0..191
    const float* W = (n < 64) ? Wq : (n < 128) ? Wk : Wv;
    const float val = W[d * 64 + (n & 63)];
    const int nt = n >> 4, l15 = n & 15;
    const int k16 = d >> 5, l4 = (d >> 3) & 3, j = d & 7;
    Bfrag[(((nt * 16 + k16) * 4 + l4) * 16 + l15) * 8 + j] = f2bf(val);
  }
  if (i < 64 * 512) {
    const int k = i >> 9;   // 0..63   (P dim)
    const int n = i & 511;  // 0..511  (D dim), consecutive -> coalesced read
    const float val = Wo[k * 512 + n];
    const int ct = n >> 4, l15 = n & 15;
    const int h = k >> 5, l4 = (k >> 3) & 3, j = k & 7;
    Wofrag[(((ct * 2 + h) * 4 + l4) * 16 + l15) * 8 + j] = f2bf(val);
  }
}

// ---------------------------------------------------------------------------
// Kernel 1: QKV projection.  Grid 1024 x 256 (4 blocks/CU, 4 waves/SIMD).
// Block = 16 rows x 192 cols; wave w owns cols w*48..+47 (3 n-tiles).
// A (16x512) converted fp32->bf16 into 16 KB swizzled LDS once (ONE barrier
// in the whole kernel); K-loop is 16 fully-unrolled steps of
// 1 ds_read_b128 + 3 coalesced frag loads + 3 MFMA, zero barriers.
// Outputs written fragment-packed for attn (q pre-scaled by 1/sqrt(P)).
// ---------------------------------------------------------------------------
__global__ __launch_bounds__(256, 4) void qkv_mfma(
    const float* __restrict__ query, const unsigned short* __restrict__ Bfrag,
    const float* __restrict__ bq, const float* __restrict__ bk,
    const float* __restrict__ bv, unsigned short* __restrict__ qfrag,
    unsigned short* __restrict__ kfrag, unsigned short* __restrict__ vfrag) {
  __shared__ __align__(16) unsigned short Aq[16 * 512];  // 16 KB

  const int tid = threadIdx.x;
  const int w = tid >> 6;
  const int l = tid & 63;
  const int l15 = l & 15;
  const int l4 = l >> 4;
  const int s0 = blockIdx.x * 16;

  // ---- Prologue: 16 query rows fp32 -> bf16 swizzled LDS tile.
  const float* qsrc = query + (size_t)s0 * D;
#pragma unroll
  for (int step = 0; step < 4; ++step) {
    const int row = step * 4 + w;  // wave-uniform
    const float* pf = qsrc + row * D + l * 8;
    const float4 x = *(const float4*)pf;
    const float4 y = *(const float4*)(pf + 4);
    bf16x8 u;
    u[0] = (short)f2bf(x.x); u[1] = (short)f2bf(x.y);
    u[2] = (short)f2bf(x.z); u[3] = (short)f2bf(x.w);
    u[4] = (short)f2bf(y.x); u[5] = (short)f2bf(y.y);
    u[6] = (short)f2bf(y.z); u[7] = (short)f2bf(y.w);
    *(bf16x8*)&Aq[row * 512 + ((l ^ (row & 7)) << 3)] = u;
  }
  __syncthreads();  // the ONLY barrier

  f32x4 acc[3];
#pragma unroll
  for (int nt = 0; nt < 3; ++nt) acc[nt] = (f32x4){0.f, 0.f, 0.f, 0.f};

#pragma unroll
  for (int k16 = 0; k16 < 16; ++k16) {
    const int aslot = (k16 * 4 + l4) ^ (l15 & 7);
    const bf16x8 af = *(const bf16x8*)&Aq[l15 * 512 + (aslot << 3)];
#pragma unroll
    for (int nt = 0; nt < 3; ++nt) {
      const int ntg = w * 3 + nt;
      const bf16x8 bf =
          *(const bf16x8*)(Bfrag + ((size_t)(ntg * 16 + k16) * 64 + l) * 8);
      acc[nt] = __builtin_amdgcn_mfma_f32_16x16x32_bf16(af, bf, acc[nt], 0, 0,
                                                        0);
    }
  }

  // ---- Epilogue: bias + scatter into fragment-packed q/k/v.
  const int b = s0 >> 11;
  const size_t bbase = (size_t)b * (S * P);
#pragma unroll
  for (int nt = 0; nt < 3; ++nt) {
    const int col = w * 48 + nt * 16 + l15;
    const int mat = col >> 6;  // uniform per 16-col tile
    const int p = col & 63;
    const float bb = ((mat == 0) ? bq : (mat == 1) ? bk : bv)[p];
#pragma unroll
    for (int r = 0; r < 4; ++r) {
      const int s = s0 + l4 * 4 + r;
      const int t = s & 2047;
      const float vl = acc[nt][r] + bb;
      if (mat == 2) {  // v: [tb][pc][lane][8], t is the K dim
        const int tb = t >> 5, chv = (t >> 3) & 3, jv = t & 7;
        const int pcv = p >> 4, rowv = p & 15;
        vfrag[bbase + (((size_t)(tb * 4 + pcv) * 4 + chv) * 16 + rowv) * 8 +
              jv] = f2bf(vl);
      } else {  // q/k: [tile][h][lane][8], p is the K dim
        const int tile = t >> 4, rowin = t & 15;
        const int h = p >> 5, chp = (p >> 3) & 3, j = p & 7;
        unsigned short* dst = (mat == 0) ? qfrag : kfrag;
        dst[bbase + (((size_t)(tile * 2 + h) * 4 + chp) * 16 + rowin) * 8 +
            j] = f2bf(mat == 0 ? vl * SCALE : vl);
      }
    }
  }
}

// ---------------------------------------------------------------------------
// Kernel 2: flash attention + fused output projection.
// Grid 256 x 512 thr (8 waves).  LDS 58 KB -> 2 blocks/CU = 4 waves/SIMD.
// Block = 64 q-rows of one batch (blk&7=batch -> XCD L2 pinning).
// Wave (qg=w&1: 32 rows, th=w>>1: 512-t quarter), 8 windows of 64 t.
// ALL q/k/v/Wo fragment loads are single coalesced 1 KB dwordx4 from L2;
// no k/v LDS, no barriers in the main loop.  Per window: kload -> QK(16 MFMA)
// -> vload (latency covered by exp chain) -> exp -> e-tile (per-wave LDS,
// XOR-swizzled) -> PV(16 MFMA).  Epilogue: cross-wave combine + normalize
// -> bf16 -> out = wnorm @ Wo + bo via MFMA from Wofrag.
// ---------------------------------------------------------------------------
__global__ __launch_bounds__(512, 4) void attn_fused(
    const unsigned short* __restrict__ qfrag,
    const unsigned short* __restrict__ kfrag,
    const unsigned short* __restrict__ vfrag,
    const unsigned short* __restrict__ Wofrag, const float* __restrict__ bo,
    float* __restrict__ out) {
  // Union region: main loop uses e_s (8 waves x 4 KB = 32 KB);
  // epilogue reuses [0,48K) as pacc (fp32 partials) + [48K,56K) as wnorm.
  __shared__ __align__(16) unsigned char smem[57344];
  __shared__ float l_s[8][32];

  const int tid = threadIdx.x;
  const int w = tid >> 6;
  const int lane = tid & 63;
  const int l15 = lane & 15;
  const int l4 = lane >> 4;
  const int qg = w & 1;
  const int th = w >> 1;

  const int blk = blockIdx.x;
  const int b = blk & 7;
  const int s0 = (blk >> 3) * 64;

  const size_t bbase = (size_t)b * (S * P);
  const unsigned short* qf = qfrag + bbase;
  const unsigned short* kf = kfrag + bbase;
  const unsigned short* vf = vfrag + bbase;

  unsigned short* e_s = (unsigned short*)smem + w * 2048;  // [2 st][16][64]

  // q A-fragments: tiles (s0>>4) + qg*2 + st.
  bf16x8 aq[2][2];
#pragma unroll
  for (int st = 0; st < 2; ++st)
#pragma unroll
    for (int h = 0; h < 2; ++h)
      aq[st][h] = *(const bf16x8*)(qf +
                                   ((size_t)(((s0 >> 4) + qg * 2 + st) * 2 + h) *
                                        64 +
                                    lane) *
                                       8);

  f32x4 acc[2][4];
#pragma unroll
  for (int st = 0; st < 2; ++st)
#pragma unroll
    for (int pc = 0; pc < 4; ++pc) acc[st][pc] = (f32x4){0.f, 0.f, 0.f, 0.f};
  float lpart[2][4] = {{0.f, 0.f, 0.f, 0.f}, {0.f, 0.f, 0.f, 0.f}};

  for (int win = 0; win < 8; ++win) {
    const int t0 = th * 512 + win * 64;

    // k fragments (coalesced 1 KB loads).
    bf16x8 bk[4][2];
#pragma unroll
    for (int nt = 0; nt < 4; ++nt)
#pragma unroll
      for (int h = 0; h < 2; ++h)
        bk[nt][h] =
            *(const bf16x8*)(kf +
                             ((size_t)(((t0 >> 4) + nt) * 2 + h) * 64 + lane) *
                                 8);

    // QK^T: 32 rows x 64 t.
    f32x4 sc[2][4];
#pragma unroll
    for (int st = 0; st < 2; ++st)
#pragma unroll
      for (int nt = 0; nt < 4; ++nt) {
        f32x4 c = (f32x4){0.f, 0.f, 0.f, 0.f};
        c = __builtin_amdgcn_mfma_f32_16x16x32_bf16(aq[st][0], bk[nt][0], c, 0,
                                                    0, 0);
        sc[st][nt] = __builtin_amdgcn_mfma_f32_16x16x32_bf16(
            aq[st][1], bk[nt][1], c, 0, 0, 0);
      }

    // v fragments issued now; exp chain below covers their L2 latency.
    bf16x8 bv[4][2];
#pragma unroll
    for (int pc = 0; pc < 4; ++pc)
#pragma unroll
      for (int kk = 0; kk < 2; ++kk)
        bv[pc][kk] =
            *(const bf16x8*)(vf +
                             ((size_t)(((t0 >> 5) + kk) * 4 + pc) * 64 + lane) *
                                 8);

    // exp -> bf16 e-tile (per-wave LDS, chunk-XOR swizzle).
#pragma unroll
    for (int st = 0; st < 2; ++st)
#pragma unroll
      for (int nt = 0; nt < 4; ++nt) {
        const int ch = nt * 2 + (l15 >> 3);
#pragma unroll
        for (int r = 0; r < 4; ++r) {
          const int rr = l4 * 4 + r;
          const unsigned short eu = f2bf(__expf(sc[st][nt][r]));
          lpart[st][r] += bf2f(eu);
          e_s[st * 1024 + rr * 64 + ((ch ^ (rr & 7)) << 3) + (l15 & 7)] = eu;
        }
      }

    // PV.
#pragma unroll
    for (int st = 0; st < 2; ++st) {
      bf16x8 ae[2];
#pragma unroll
      for (int kk = 0; kk < 2; ++kk)
        ae[kk] = *(const bf16x8*)&e_s[st * 1024 + l15 * 64 +
                                      (((kk * 4 + l4) ^ (l15 & 7)) << 3)];
#pragma unroll
      for (int pc = 0; pc < 4; ++pc) {
        acc[st][pc] = __builtin_amdgcn_mfma_f32_16x16x32_bf16(
            ae[0], bv[pc][0], acc[st][pc], 0, 0, 0);
        acc[st][pc] = __builtin_amdgcn_mfma_f32_16x16x32_bf16(
            ae[1], bv[pc][1], acc[st][pc], 0, 0, 0);
      }
    }
  }

  // ---- Row-sums across the 16 col-lanes.
#pragma unroll
  for (int st = 0; st < 2; ++st)
#pragma unroll
    for (int r = 0; r < 4; ++r) {
      float v = lpart[st][r];
      v += __shfl_xor(v, 1, 64);
      v += __shfl_xor(v, 2, 64);
      v += __shfl_xor(v, 4, 64);
      v += __shfl_xor(v, 8, 64);
      if (l15 == 0) l_s[w][st * 16 + l4 * 4 + r] = v;
    }

  __syncthreads();  // everyone done with e_s before pacc aliases it

  float* pacc = (float*)smem;  // [2 qg][3 th-1][32 rows][64 p]
  if (th > 0) {
#pragma unroll
    for (int st = 0; st < 2; ++st)
#pragma unroll
      for (int pc = 0; pc < 4; ++pc)
#pragma unroll
        for (int r = 0; r < 4; ++r)
          pacc[((size_t)(qg * 3 + th - 1) * 32 + st * 16 + l4 * 4 + r) * 64 +
               pc * 16 + l15] = acc[st][pc][r];
  }
  __syncthreads();

  unsigned short* wnorm = (unsigned short*)(smem + 49152);  // [2][32][64]
  if (th == 0) {
#pragma unroll
    for (int st = 0; st < 2; ++st) {
      float rl[4];
#pragma unroll
      for (int r = 0; r < 4; ++r) {
        const int row = st * 16 + l4 * 4 + r;
        rl[r] = 1.f / (l_s[qg][row] + l_s[2 + qg][row] + l_s[4 + qg][row] +
                       l_s[6 + qg][row]);
      }
#pragma unroll
      for (int pc = 0; pc < 4; ++pc)
#pragma unroll
        for (int r = 0; r < 4; ++r) {
          float s = acc[st][pc][r];
#pragma unroll
          for (int j = 0; j < 3; ++j)
            s += pacc[((size_t)(qg * 3 + j) * 32 + st * 16 + l4 * 4 + r) * 64 +
                      pc * 16 + l15];
          wnorm[(qg * 32 + st * 16 + l4 * 4 + r) * 64 + pc * 16 + l15] =
              f2bf(s * rl[r]);
        }
    }
  }
  __syncthreads();

  // ---- Fused output projection: wave = 16 rows x 256 cols, Wo from Wofrag.
  const int sub = w & 3;     // 16-row subtile of the 64
  const int chalf = w >> 2;  // 256-col half
  const bf16x8 a0 = *(const bf16x8*)&wnorm[(sub * 16 + l15) * 64 + l4 * 8];
  const bf16x8 a1 =
      *(const bf16x8*)&wnorm[(sub * 16 + l15) * 64 + 32 + l4 * 8];
  const size_t orow0 = (size_t)b * S + s0 + sub * 16;
#pragma unroll
  for (int ct = 0; ct < 16; ++ct) {
    const int ctg = chalf * 16 + ct;
    const bf16x8 b0 =
        *(const bf16x8*)(Wofrag + ((size_t)(ctg * 2 + 0) * 64 + lane) * 8);
    const bf16x8 b1 =
        *(const bf16x8*)(Wofrag + ((size_t)(ctg * 2 + 1) * 64 + lane) * 8);
    f32x4 c = (f32x4){0.f, 0.f, 0.f, 0.f};
    c = __builtin_amdgcn_mfma_f32_16x16x32_bf16(a0, b0, c, 0, 0, 0);
    c = __builtin_amdgcn_mfma_f32_16x16x32_bf16(a1, b1, c, 0, 0, 0);
    const int col = ctg * 16 + l15;
    const float bb = bo[col];
#pragma unroll
    for (int r = 0; r < 4; ++r)
      out[(orow0 + l4 * 4 + r) * D + col] = c[r] + bb;
  }
}

// ---------------------------------------------------------------------------
extern "C" void kernel_launch(void* const* d_in, const int* in_sizes, int n_in,
                              void* d_out, int out_size, void* d_ws,
                              size_t ws_size, hipStream_t stream) {
  const float* query = (const float*)d_in[0];
  // d_in[1] = attention_mask: unused (per-row additive constant -> softmax no-op)
  const float* Wq = (const float*)d_in[2];
  const float* bq = (const float*)d_in[3];
  const float* Wk = (const float*)d_in[4];
  const float* bk = (const float*)d_in[5];
  const float* Wv = (const float*)d_in[6];
  const float* bv = (const float*)d_in[7];
  const float* Wo = (const float*)d_in[8];
  const float* bo = (const float*)d_in[9];
  float* out = (float*)d_out;

  // Workspace (bf16): qfrag 2MB | kfrag 2MB | vfrag 2MB | Bfrag 192KB | Wofrag 64KB
  const size_t proj = (size_t)B * S * P;  // 1,048,576
  unsigned short* qfr = (unsigned short*)d_ws;
  unsigned short* kfr = qfr + proj;
  unsigned short* vfr = kfr + proj;
  unsigned short* Bfrag = vfr + proj;
  unsigned short* Wofrag = Bfrag + 192 * 512;

  prep_w<<<384, 256, 0, stream>>>(Wq, Wk, Wv, Wo, Bfrag, Wofrag);
  qkv_mfma<<<1024, 256, 0, stream>>>(query, Bfrag, bq, bk, bv, qfr, kfr, vfr);
  attn_fused<<<256, 512, 0, stream>>>(qfr, kfr, vfr, Wofrag, bo, out);
}

// Round 7
// 139.890 us; speedup vs baseline: 1.0181x; 1.0181x over previous
//
#include <hip/hip_runtime.h>
#include <hip/hip_bf16.h>
#include <math.h>

// Problem constants (from reference)
constexpr int B = 8;
constexpr int S = 2048;
constexpr int D = 512;
constexpr int P = 64;
constexpr float SCALE = 0.125f;  // 1/sqrt(P)

typedef short bf16x8 __attribute__((ext_vector_type(8)));
typedef float f32x4 __attribute__((ext_vector_type(4)));
typedef unsigned int u32;

__device__ __forceinline__ unsigned short f2bf(float x) {
  __hip_bfloat16 h = __float2bfloat16(x);
  return __builtin_bit_cast(unsigned short, h);
}
__device__ __forceinline__ float bf2f(unsigned short u) {
  unsigned int v = (unsigned int)u << 16;
  return __builtin_bit_cast(float, v);
}

// ===========================================================================
// Fragment-packed layouts (as round 6): every MFMA fragment is a contiguous
// 64-lane x 16 B = 1 KB lane-ordered chunk -> one coalesced dwordx4 per load.
//  Bfrag  [12 ntile][16 k16][64 lane][8]   : WqWkWv cat (192 cols, K=512)
//  Wofrag [32 ct][2 h][64 lane][8]         : Wo (512 cols, K=64)
//  qfrag/kfrag [b][128 tile][2 h][64][8]   : tile=16 rows, h=K-half
//  vfrag  [b][64 tb][4 pc][64][8]          : tb=32 t's, pc=16 p's (t = K dim)
// NEW this round: STAGGERED access order everywhere (blocks start their
// K/window loops at different phases) to break the L2 same-line hotspot
// created by lockstep blocks, + 4 waves/SIMD in attn.
// ===========================================================================

// ---------------------------------------------------------------------------
// Kernel 0: weight prep -> fragment-packed bf16.
// ---------------------------------------------------------------------------
__global__ __launch_bounds__(256) void prep_w(
    const float* __restrict__ Wq, const float* __restrict__ Wk,
    const float* __restrict__ Wv, const float* __restrict__ Wo,
    unsigned short* __restrict__ Bfrag, unsigned short* __restrict__ Wofrag) {
  const int i = blockIdx.x * 256 + threadIdx.x;
  if (i < 192 * 512) {
    const int d = i / 192;        // K index 0..511
    const int n = i - d * 192;    // output col 0..191
    const float* W = (n < 64) ? Wq : (n < 128) ? Wk : Wv;
    const float val = W[d * 64 + (n & 63)];
    const int nt = n >> 4, l15 = n & 15;
    const int k16 = d >> 5, l4 = (d >> 3) & 3, j = d & 7;
    Bfrag[(((nt * 16 + k16) * 4 + l4) * 16 + l15) * 8 + j] = f2bf(val);
  }
  if (i < 64 * 512) {
    const int k = i >> 9;   // 0..63   (P dim)
    const int n = i & 511;  // 0..511  (D dim)
    const float val = Wo[k * 512 + n];
    const int ct = n >> 4, l15 = n & 15;
    const int h = k >> 5, l4 = (k >> 3) & 3, j = k & 7;
    Wofrag[(((ct * 2 + h) * 4 + l4) * 16 + l15) * 8 + j] = f2bf(val);
  }
}

// ---------------------------------------------------------------------------
// Kernel 1: QKV projection.  Grid 1024 x 256 (4 blocks/CU, 4 waves/SIMD).
// Block = 16 rows x 192 cols; wave w owns cols w*48..+47 (3 n-tiles).
// K-loop STAGGERED: block starts at chunk (blockIdx&15) so the 1024 blocks
// don't all hammer the same Bfrag lines simultaneously (sum order free).
// One barrier total; zero barriers in the K-loop.
// ---------------------------------------------------------------------------
__global__ __launch_bounds__(256, 4) void qkv_mfma(
    const float* __restrict__ query, const unsigned short* __restrict__ Bfrag,
    const float* __restrict__ bq, const float* __restrict__ bk,
    const float* __restrict__ bv, unsigned short* __restrict__ qfrag,
    unsigned short* __restrict__ kfrag, unsigned short* __restrict__ vfrag) {
  __shared__ __align__(16) unsigned short Aq[16 * 512];  // 16 KB

  const int tid = threadIdx.x;
  const int w = tid >> 6;
  const int l = tid & 63;
  const int l15 = l & 15;
  const int l4 = l >> 4;
  const int s0 = blockIdx.x * 16;
  const int kb0 = blockIdx.x & 15;  // K-phase stagger

  // ---- Prologue: 16 query rows fp32 -> bf16 swizzled LDS tile.
  const float* qsrc = query + (size_t)s0 * D;
#pragma unroll
  for (int step = 0; step < 4; ++step) {
    const int row = step * 4 + w;  // wave-uniform
    const float* pf = qsrc + row * D + l * 8;
    const float4 x = *(const float4*)pf;
    const float4 y = *(const float4*)(pf + 4);
    bf16x8 u;
    u[0] = (short)f2bf(x.x); u[1] = (short)f2bf(x.y);
    u[2] = (short)f2bf(x.z); u[3] = (short)f2bf(x.w);
    u[4] = (short)f2bf(y.x); u[5] = (short)f2bf(y.y);
    u[6] = (short)f2bf(y.z); u[7] = (short)f2bf(y.w);
    *(bf16x8*)&Aq[row * 512 + ((l ^ (row & 7)) << 3)] = u;
  }
  __syncthreads();  // the ONLY barrier

  f32x4 acc[3];
#pragma unroll
  for (int nt = 0; nt < 3; ++nt) acc[nt] = (f32x4){0.f, 0.f, 0.f, 0.f};

#pragma unroll
  for (int kk = 0; kk < 16; ++kk) {
    const int k16 = (kk + kb0) & 15;  // staggered K order
    const int aslot = (k16 * 4 + l4) ^ (l15 & 7);
    const bf16x8 af = *(const bf16x8*)&Aq[l15 * 512 + (aslot << 3)];
#pragma unroll
    for (int nt = 0; nt < 3; ++nt) {
      const int ntg = w * 3 + nt;
      const bf16x8 bf =
          *(const bf16x8*)(Bfrag + ((size_t)(ntg * 16 + k16) * 64 + l) * 8);
      acc[nt] = __builtin_amdgcn_mfma_f32_16x16x32_bf16(af, bf, acc[nt], 0, 0,
                                                        0);
    }
  }

  // ---- Epilogue: bias + scatter into fragment-packed q/k/v.
  const int b = s0 >> 11;
  const size_t bbase = (size_t)b * (S * P);
#pragma unroll
  for (int nt = 0; nt < 3; ++nt) {
    const int col = w * 48 + nt * 16 + l15;
    const int mat = col >> 6;  // uniform per 16-col tile
    const int p = col & 63;
    const float bb = ((mat == 0) ? bq : (mat == 1) ? bk : bv)[p];
#pragma unroll
    for (int r = 0; r < 4; ++r) {
      const int s = s0 + l4 * 4 + r;
      const int t = s & 2047;
      const float vl = acc[nt][r] + bb;
      if (mat == 2) {  // v: [tb][pc][lane][8], t is the K dim
        const int tb = t >> 5, chv = (t >> 3) & 3, jv = t & 7;
        const int pcv = p >> 4, rowv = p & 15;
        vfrag[bbase + (((size_t)(tb * 4 + pcv) * 4 + chv) * 16 + rowv) * 8 +
              jv] = f2bf(vl);
      } else {  // q/k: [tile][h][lane][8], p is the K dim
        const int tile = t >> 4, rowin = t & 15;
        const int h = p >> 5, chp = (p >> 3) & 3, j = p & 7;
        unsigned short* dst = (mat == 0) ? qfrag : kfrag;
        dst[bbase + (((size_t)(tile * 2 + h) * 4 + chp) * 16 + rowin) * 8 +
            j] = f2bf(mat == 0 ? vl * SCALE : vl);
      }
    }
  }
}

// ---------------------------------------------------------------------------
// Kernel 2: flash attention + fused output projection (v7).
// Grid 256 x 1024 thr (16 waves -> 4 waves/SIMD, 2x round 6).
// Block = 64 q-rows of one batch (blk&7=batch -> XCD L2 pinning).
// Wave (qg=w&1: 32 rows, th=w>>1: 256-t eighth), 4 windows of 64 t,
// window order STAGGERED by q-tile ((blk>>3)&3) so the 32 blocks of a batch
// don't read identical k/v lines in lockstep (softmax sums commute).
// Per-wave e-tile DOUBLE-buffered (8 KB/wave) so consecutive windows' LDS
// ops don't serialize.  No barriers in the main loop.
// Epilogue: 8-way t-partial combine + normalize -> bf16 -> out = wnorm @ Wo.
// ---------------------------------------------------------------------------
__global__ __launch_bounds__(1024, 4) void attn_fused(
    const unsigned short* __restrict__ qfrag,
    const unsigned short* __restrict__ kfrag,
    const unsigned short* __restrict__ vfrag,
    const unsigned short* __restrict__ Wofrag, const float* __restrict__ bo,
    float* __restrict__ out) {
  // Main loop: e_s = 16 waves x 8 KB (double-buffered) = 128 KB.
  // Epilogue aliases: pacc [2][7][32][64] f32 = 112 KB at offset 0;
  //                   wnorm [64][64] bf16 = 8 KB at offset 114688.
  __shared__ __align__(16) unsigned char smem[131072];
  __shared__ float l_s[16][32];

  const int tid = threadIdx.x;
  const int w = tid >> 6;
  const int lane = tid & 63;
  const int l15 = lane & 15;
  const int l4 = lane >> 4;
  const int qg = w & 1;   // 32-row group
  const int th = w >> 1;  // 256-t eighth: t in [th*256, th*256+256)

  const int blk = blockIdx.x;
  const int b = blk & 7;
  const int qt = blk >> 3;     // 0..31
  const int s0 = qt * 64;
  const int wst = qt & 3;      // window-phase stagger

  const size_t bbase = (size_t)b * (S * P);
  const unsigned short* qf = qfrag + bbase;
  const unsigned short* kf = kfrag + bbase;
  const unsigned short* vf = vfrag + bbase;

  unsigned short* e_w = (unsigned short*)smem + w * 4096;  // [2 buf][2 st][16][64]

  // q A-fragments: tiles (s0>>4) + qg*2 + st.
  bf16x8 aq[2][2];
#pragma unroll
  for (int st = 0; st < 2; ++st)
#pragma unroll
    for (int h = 0; h < 2; ++h)
      aq[st][h] =
          *(const bf16x8*)(qf +
                           ((size_t)(((s0 >> 4) + qg * 2 + st) * 2 + h) * 64 +
                            lane) *
                               8);

  f32x4 acc[2][4];
#pragma unroll
  for (int st = 0; st < 2; ++st)
#pragma unroll
    for (int pc = 0; pc < 4; ++pc) acc[st][pc] = (f32x4){0.f, 0.f, 0.f, 0.f};
  float lpart[2][4] = {{0.f, 0.f, 0.f, 0.f}, {0.f, 0.f, 0.f, 0.f}};

  for (int win = 0; win < 4; ++win) {
    const int wi = (win + wst) & 3;           // staggered window
    const int t0 = th * 256 + wi * 64;
    unsigned short* e_s = e_w + (win & 1) * 2048;  // double buffer

    // k fragments (8 coalesced 1 KB loads).
    bf16x8 bk[4][2];
#pragma unroll
    for (int nt = 0; nt < 4; ++nt)
#pragma unroll
      for (int h = 0; h < 2; ++h)
        bk[nt][h] =
            *(const bf16x8*)(kf +
                             ((size_t)(((t0 >> 4) + nt) * 2 + h) * 64 + lane) *
                                 8);

    // QK^T + exp per subtile (keeps score regs short-lived).
#pragma unroll
    for (int st = 0; st < 2; ++st) {
      f32x4 sc[4];
#pragma unroll
      for (int nt = 0; nt < 4; ++nt) {
        f32x4 c = (f32x4){0.f, 0.f, 0.f, 0.f};
        c = __builtin_amdgcn_mfma_f32_16x16x32_bf16(aq[st][0], bk[nt][0], c, 0,
                                                    0, 0);
        sc[nt] = __builtin_amdgcn_mfma_f32_16x16x32_bf16(aq[st][1], bk[nt][1],
                                                         c, 0, 0, 0);
      }
#pragma unroll
      for (int nt = 0; nt < 4; ++nt) {
        const int ch = nt * 2 + (l15 >> 3);
#pragma unroll
        for (int r = 0; r < 4; ++r) {
          const int rr = l4 * 4 + r;
          const unsigned short eu = f2bf(__expf(sc[nt][r]));
          lpart[st][r] += bf2f(eu);
          e_s[st * 1024 + rr * 64 + ((ch ^ (rr & 7)) << 3) + (l15 & 7)] = eu;
        }
      }
    }

    // v fragments (latency covered by the exp/store chain above finishing).
    bf16x8 bv[4][2];
#pragma unroll
    for (int pc = 0; pc < 4; ++pc)
#pragma unroll
      for (int kk = 0; kk < 2; ++kk)
        bv[pc][kk] =
            *(const bf16x8*)(vf +
                             ((size_t)(((t0 >> 5) + kk) * 4 + pc) * 64 + lane) *
                                 8);

    // PV.
#pragma unroll
    for (int st = 0; st < 2; ++st) {
      bf16x8 ae[2];
#pragma unroll
      for (int kk = 0; kk < 2; ++kk)
        ae[kk] = *(const bf16x8*)&e_s[st * 1024 + l15 * 64 +
                                      (((kk * 4 + l4) ^ (l15 & 7)) << 3)];
#pragma unroll
      for (int pc = 0; pc < 4; ++pc) {
        acc[st][pc] = __builtin_amdgcn_mfma_f32_16x16x32_bf16(
            ae[0], bv[pc][0], acc[st][pc], 0, 0, 0);
        acc[st][pc] = __builtin_amdgcn_mfma_f32_16x16x32_bf16(
            ae[1], bv[pc][1], acc[st][pc], 0, 0, 0);
      }
    }
  }

  // ---- Row-sums across the 16 col-lanes.
#pragma unroll
  for (int st = 0; st < 2; ++st)
#pragma unroll
    for (int r = 0; r < 4; ++r) {
      float v = lpart[st][r];
      v += __shfl_xor(v, 1, 64);
      v += __shfl_xor(v, 2, 64);
      v += __shfl_xor(v, 4, 64);
      v += __shfl_xor(v, 8, 64);
      if (l15 == 0) l_s[w][st * 16 + l4 * 4 + r] = v;
    }

  __syncthreads();  // all waves done with e_s before pacc aliases it

  float* pacc = (float*)smem;  // [2 qg][7][32 rows][64 p]
  if (th > 0) {
#pragma unroll
    for (int st = 0; st < 2; ++st)
#pragma unroll
      for (int pc = 0; pc < 4; ++pc)
#pragma unroll
        for (int r = 0; r < 4; ++r)
          pacc[((size_t)(qg * 7 + th - 1) * 32 + st * 16 + l4 * 4 + r) * 64 +
               pc * 16 + l15] = acc[st][pc][r];
  }
  __syncthreads();

  unsigned short* wnorm = (unsigned short*)(smem + 114688);  // [64][64]
  if (th == 0) {
#pragma unroll
    for (int st = 0; st < 2; ++st) {
      float rl[4];
#pragma unroll
      for (int r = 0; r < 4; ++r) {
        const int row = st * 16 + l4 * 4 + r;
        float ls = 0.f;
#pragma unroll
        for (int t8 = 0; t8 < 8; ++t8) ls += l_s[t8 * 2 + qg][row];
        rl[r] = 1.f / ls;
      }
#pragma unroll
      for (int pc = 0; pc < 4; ++pc)
#pragma unroll
        for (int r = 0; r < 4; ++r) {
          float s = acc[st][pc][r];
#pragma unroll
          for (int j = 0; j < 7; ++j)
            s += pacc[((size_t)(qg * 7 + j) * 32 + st * 16 + l4 * 4 + r) * 64 +
                      pc * 16 + l15];
          wnorm[(qg * 32 + st * 16 + l4 * 4 + r) * 64 + pc * 16 + l15] =
              f2bf(s * rl[r]);
        }
    }
  }
  __syncthreads();

  // ---- Fused output projection: 16 waves = (4 row-subtiles) x (4 col-128s).
  const int sub = w & 3;    // 16-row subtile
  const int chq = w >> 2;   // 128-col quarter
  const bf16x8 a0 = *(const bf16x8*)&wnorm[(sub * 16 + l15) * 64 + l4 * 8];
  const bf16x8 a1 =
      *(const bf16x8*)&wnorm[(sub * 16 + l15) * 64 + 32 + l4 * 8];
  const size_t orow0 = (size_t)b * S + s0 + sub * 16;
#pragma unroll
  for (int ct = 0; ct < 8; ++ct) {
    const int ctg = chq * 8 + ((ct + (blk & 7)) & 7);  // staggered Wo tiles
    const bf16x8 b0 =
        *(const bf16x8*)(Wofrag + ((size_t)(ctg * 2 + 0) * 64 + lane) * 8);
    const bf16x8 b1 =
        *(const bf16x8*)(Wofrag + ((size_t)(ctg * 2 + 1) * 64 + lane) * 8);
    f32x4 c = (f32x4){0.f, 0.f, 0.f, 0.f};
    c = __builtin_amdgcn_mfma_f32_16x16x32_bf16(a0, b0, c, 0, 0, 0);
    c = __builtin_amdgcn_mfma_f32_16x16x32_bf16(a1, b1, c, 0, 0, 0);
    const int col = ctg * 16 + l15;
    const float bb = bo[col];
#pragma unroll
    for (int r = 0; r < 4; ++r)
      out[(orow0 + l4 * 4 + r) * D + col] = c[r] + bb;
  }
}

// ---------------------------------------------------------------------------
extern "C" void kernel_launch(void* const* d_in, const int* in_sizes, int n_in,
                              void* d_out, int out_size, void* d_ws,
                              size_t ws_size, hipStream_t stream) {
  const float* query = (const float*)d_in[0];
  // d_in[1] = attention_mask: unused (per-row additive constant -> softmax no-op)
  const float* Wq = (const float*)d_in[2];
  const float* bq = (const float*)d_in[3];
  const float* Wk = (const float*)d_in[4];
  const float* bk = (const float*)d_in[5];
  const float* Wv = (const float*)d_in[6];
  const float* bv = (const float*)d_in[7];
  const float* Wo = (const float*)d_in[8];
  const float* bo = (const float*)d_in[9];
  float* out = (float*)d_out;

  // Workspace (bf16): qfrag 2MB | kfrag 2MB | vfrag 2MB | Bfrag 192KB | Wofrag 64KB
  const size_t proj = (size_t)B * S * P;  // 1,048,576
  unsigned short* qfr = (unsigned short*)d_ws;
  unsigned short* kfr = qfr + proj;
  unsigned short* vfr = kfr + proj;
  unsigned short* Bfrag = vfr + proj;
  unsigned short* Wofrag = Bfrag + 192 * 512;

  prep_w<<<384, 256, 0, stream>>>(Wq, Wk, Wv, Wo, Bfrag, Wofrag);
  qkv_mfma<<<1024, 256, 0, stream>>>(query, Bfrag, bq, bk, bv, qfr, kfr, vfr);
  attn_fused<<<256, 1024, 0, stream>>>(qfr, kfr, vfr, Wofrag, bo, out);
}